// Round 5
// baseline (649.550 us; speedup 1.0000x reference)
//
#include <hip/hip_runtime.h>
#include <hip/hip_fp16.h>

// 2-layer GCN: out = gcn(relu(gcn(x,W1,b1,e0)), W2, b2, e1)
// R1: atomic-cursor CSR fill -> 16x write-amp -> bucket partition.
// R2: node-granular global-atomic histogram -> bucket histogram + fused
//     per-bucket finalize; dinv folded into GEMM epilogue (H' fp16 in R3).
// R3: NPB 256->64 fixed k_bfin starvation but...
// R4: ...regressed k_bscatter: 10-edge runs -> 6x write-amp + cross-XCD
//     line bounce (80MB writes for 12.8MB). Fix: block-PRIVATE dense
//     partition -- each block sorts its 16K-edge chunk by bucket into its
//     own packed[k*CHUNK..] region (runs abut, write-amp 1.0, single-XCD
//     ownership) + run-offset table runoff[k][b]. Histogram pass of the
//     scatter subsumes k_bhist/k_bscan (deleted). NPB back to 128.

#define NPB   128
#define BSH   7
#define BMSK  127
#define MAXB  1024   // >= B = ceil(100000/128) = 782
#define CHUNK 16384
#define MAXCH 256    // >= nchunk = ceil(E/CHUNK) = 196

// Partition chunk k by dst-bucket into private region packed[k*CHUNK..].
// Emits runoff[k][b] (start of bucket-b run within chunk, exclusive prefix;
// runoff[k][B] = chunk count) and accumulates bucket totals into btot.
__global__ __launch_bounds__(256) void k_scatter(const int* __restrict__ src,
                                                 const int* __restrict__ dst,
                                                 int* __restrict__ runoff,
                                                 int* __restrict__ btot,
                                                 int* __restrict__ packed,
                                                 int E, int B) {
  __shared__ int hist[MAXB];
  __shared__ int wsum[4];
  int t = threadIdx.x;
  int k = blockIdx.x;
  int e0 = k * CHUNK;
  int cnt = min(CHUNK, E - e0);
  for (int b = t; b < B; b += 256) hist[b] = 0;
  __syncthreads();
  // pass 1: histogram
  for (int i = t; i < cnt; i += 256)
    atomicAdd(&hist[dst[e0 + i] >> BSH], 1);
  __syncthreads();
  // block scan over B bins (256 threads x 4 items)
  int i0 = t * 4;
  int v0 = (i0 + 0 < B) ? hist[i0 + 0] : 0;
  int v1 = (i0 + 1 < B) ? hist[i0 + 1] : 0;
  int v2 = (i0 + 2 < B) ? hist[i0 + 2] : 0;
  int v3 = (i0 + 3 < B) ? hist[i0 + 3] : 0;
  // fold per-block bucket counts into global totals (3KB array, cached)
  if (v0) atomicAdd(&btot[i0 + 0], v0);
  if (v1) atomicAdd(&btot[i0 + 1], v1);
  if (v2) atomicAdd(&btot[i0 + 2], v2);
  if (v3) atomicAdd(&btot[i0 + 3], v3);
  int tsum = v0 + v1 + v2 + v3;
  int lane = t & 63, wid = t >> 6;
  int x = tsum;
#pragma unroll
  for (int d = 1; d < 64; d <<= 1) {
    int y = __shfl_up(x, d, 64);
    if (lane >= d) x += y;
  }
  if (lane == 63) wsum[wid] = x;
  __syncthreads();
  int wofs = 0;
  for (int ww = 0; ww < wid; ++ww) wofs += wsum[ww];
  int excl = wofs + x - tsum;
  hist[i0 + 0] = excl;                 // becomes run start / fill cursor
  hist[i0 + 1] = excl + v0;
  hist[i0 + 2] = excl + v0 + v1;
  hist[i0 + 3] = excl + v0 + v1 + v2;
  __syncthreads();
  int* row = runoff + (size_t)k * (B + 1);
  for (int b = t; b < B; b += 256) row[b] = hist[b];
  if (t == 0) row[B] = cnt;
  __syncthreads();
  // pass 2: scatter into private region (dense: runs abut, write-amp 1.0)
  for (int i = t; i < cnt; i += 256) {
    int d = dst[e0 + i];
    int b = d >> BSH;
    int loc = atomicAdd(&hist[b], 1);
    packed[e0 + loc] = (src[e0 + i] << BSH) | (d & BMSK);
  }
}

// Exclusive scan of bucket totals -> bbase[0..B], bbase[B]=E. One block.
__global__ __launch_bounds__(1024) void k_btot(const int* __restrict__ btot,
                                               int* __restrict__ bbase,
                                               int B, int E) {
  __shared__ int wsum[16];
  int t = threadIdx.x;
  int c = (t < B) ? btot[t] : 0;
  int lane = t & 63, wid = t >> 6;
  int x = c;
#pragma unroll
  for (int d = 1; d < 64; d <<= 1) {
    int y = __shfl_up(x, d, 64);
    if (lane >= d) x += y;
  }
  if (lane == 63) wsum[wid] = x;
  __syncthreads();
  int wofs = 0;
  for (int ww = 0; ww < wid; ++ww) wofs += wsum[ww];
  if (t < B) bbase[t] = wofs + x - c;
  if (t == 0) bbase[B] = E;
}

// Per-bucket finalize: stream this bucket's runs (one per chunk) -> LDS node
// counts -> scan -> off/dinv -> csr fill into contiguous global segment.
__global__ __launch_bounds__(256) void k_bfin(const int* __restrict__ packed,
                                              const int* __restrict__ runoff,
                                              const int* __restrict__ bbase,
                                              int* __restrict__ off,
                                              float* __restrict__ dinv,
                                              int* __restrict__ csr,
                                              int N, int B, int nchunk) {
  __shared__ int cnt[NPB];
  __shared__ int cur[NPB];
  __shared__ int ro[MAXCH];
  __shared__ int rl[MAXCH];
  __shared__ int wsum[4];
  int t = threadIdx.x;
  int b = blockIdx.x;
  for (int k = t; k < nchunk; k += 256) {
    const int* row = runoff + (size_t)k * (B + 1);
    int s = row[b], e = row[b + 1];
    ro[k] = k * CHUNK + s;
    rl[k] = e - s;
  }
  if (t < NPB) cnt[t] = 0;
  __syncthreads();
  int lane = t & 63, w = t >> 6;
  // pass 1: per-node counts
  for (int k = w; k < nchunk; k += 4) {
    int base = ro[k], len = rl[k];
    for (int j = lane; j < len; j += 64)
      atomicAdd(&cnt[packed[base + j] & BMSK], 1);
  }
  __syncthreads();
  // scan NPB=128 counts (all threads run the machinery; t>=NPB contributes 0)
  int c = (t < NPB) ? cnt[t] : 0;
  int x = c;
#pragma unroll
  for (int d = 1; d < 64; d <<= 1) {
    int y = __shfl_up(x, d, 64);
    if (lane >= d) x += y;
  }
  if (lane == 63) wsum[w] = x;
  __syncthreads();
  int wofs = 0;
  for (int ww = 0; ww < w; ++ww) wofs += wsum[ww];
  int excl = bbase[b] + wofs + x - c;
  int v = (b << BSH) + t;
  if (t < NPB && v < N) {
    off[v] = excl;
    dinv[v] = rsqrtf((float)(c + 1));  // +1 self-loop
  }
  if (t < NPB) cur[t] = excl;
  if (b == B - 1 && t == 0) off[N] = bbase[B];
  __syncthreads();
  // pass 2: fill csr (runs re-read, L2-hot)
  for (int k = w; k < nchunk; k += 4) {
    int base = ro[k], len = rl[k];
    for (int j = lane; j < len; j += 64) {
      int e = packed[base + j];
      int p = atomicAdd(&cur[e & BMSK], 1);
      csr[p] = e >> BSH;
    }
  }
}

// H'[v] = fp16((X @ W)[v] * dinv[v]).  W (16KB) in LDS; 4 nodes/block-iter.
__global__ __launch_bounds__(256) void k_gemm64(const float* __restrict__ X,
                                                const float* __restrict__ W,
                                                const float* __restrict__ dinv,
                                                __half* __restrict__ H, int N) {
  __shared__ float Wl[4096];
  __shared__ float Xl[256];
  for (int t = threadIdx.x; t < 4096; t += 256) Wl[t] = W[t];
  int j = threadIdx.x & 63;
  int nl = threadIdx.x >> 6;
  for (int base = blockIdx.x * 4; base < N; base += gridDim.x * 4) {
    __syncthreads();
    int gi = base * 64 + threadIdx.x;
    Xl[threadIdx.x] = (gi < N * 64) ? X[gi] : 0.f;
    __syncthreads();
    int v = base + nl;
    if (v < N) {
      float acc = 0.f;
#pragma unroll
      for (int k = 0; k < 64; k += 4) {
        acc = fmaf(Xl[nl * 64 + k + 0], Wl[(k + 0) * 64 + j], acc);
        acc = fmaf(Xl[nl * 64 + k + 1], Wl[(k + 1) * 64 + j], acc);
        acc = fmaf(Xl[nl * 64 + k + 2], Wl[(k + 2) * 64 + j], acc);
        acc = fmaf(Xl[nl * 64 + k + 3], Wl[(k + 3) * 64 + j], acc);
      }
      H[v * 64 + j] = __float2half_rn(acc * dinv[v]);
    }
  }
}

// Pull aggregation: one wave per node, lane = feature; fp16 gathers,
// fp32 accumulate. csr read 64-per-wave-load, shfl-broadcast.
template <bool RELU>
__global__ __launch_bounds__(256) void k_agg(const __half* __restrict__ H,
                                             const int* __restrict__ csr,
                                             const int* __restrict__ off,
                                             const float* __restrict__ dinv,
                                             const float* __restrict__ bias,
                                             float* __restrict__ out, int N) {
  int wid = (blockIdx.x * blockDim.x + threadIdx.x) >> 6;
  int lane = threadIdx.x & 63;
  if (wid >= N) return;
  int beg = off[wid];
  int num = off[wid + 1] - beg;
  float acc = __half2float(H[wid * 64 + lane]);  // self-loop (pre-scaled)
  for (int base = 0; base < num; base += 64) {
    int navail = min(64, num - base);
    int sv = (base + lane < num) ? csr[beg + base + lane] : 0;
    int j = 0;
    for (; j + 4 <= navail; j += 4) {
      int s0 = __shfl(sv, j + 0), s1 = __shfl(sv, j + 1);
      int s2 = __shfl(sv, j + 2), s3 = __shfl(sv, j + 3);
      float h0 = __half2float(H[s0 * 64 + lane]);
      float h1 = __half2float(H[s1 * 64 + lane]);
      float h2 = __half2float(H[s2 * 64 + lane]);
      float h3 = __half2float(H[s3 * 64 + lane]);
      acc += h0; acc += h1; acc += h2; acc += h3;
    }
    for (; j < navail; ++j) acc += __half2float(H[__shfl(sv, j) * 64 + lane]);
  }
  acc = fmaf(acc, dinv[wid], bias[lane]);
  if (RELU) acc = fmaxf(acc, 0.f);
  out[wid * 64 + lane] = acc;
}

extern "C" void kernel_launch(void* const* d_in, const int* in_sizes, int n_in,
                              void* d_out, int out_size, void* d_ws, size_t ws_size,
                              hipStream_t stream) {
  const float* x  = (const float*)d_in[0];
  const float* W1 = (const float*)d_in[1];
  const float* b1 = (const float*)d_in[2];
  const float* W2 = (const float*)d_in[3];
  const float* b2 = (const float*)d_in[4];
  const int*   e0 = (const int*)d_in[5];
  const int*   e1 = (const int*)d_in[6];
  float* out = (float*)d_out;

  const int N = in_sizes[0] / 64;      // 100000
  const int E = in_sizes[5] / 2;       // 3200000
  const int B = (N + NPB - 1) / NPB;   // 782
  const int nchunk = (E + CHUNK - 1) / CHUNK;  // 196
  const int* src0 = e0;     const int* dst0 = e0 + E;
  const int* src1 = e1;     const int* dst1 = e1 + E;

  char* w = (char*)d_ws;
  size_t o = 0;
  auto carve = [&](size_t bytes) -> void* {
    void* p = w + o;
    o = (o + bytes + 255) & ~(size_t)255;
    return p;
  };
  int* btot12 = (int*)carve((size_t)2 * MAXB * 4);  // zero-init
  int* btot1 = btot12;
  int* btot2 = btot12 + MAXB;
  int* bbase1 = (int*)carve((MAXB + 1) * 4);
  int* bbase2 = (int*)carve((MAXB + 1) * 4);
  int* runoff = (int*)carve((size_t)MAXCH * (MAXB + 1) * 4);  // shared
  int* off1 = (int*)carve((size_t)(N + 1) * 4);
  int* off2 = (int*)carve((size_t)(N + 1) * 4);
  float* dinv1 = (float*)carve((size_t)N * 4);
  float* dinv2 = (float*)carve((size_t)N * 4);
  int* packed = (int*)carve((size_t)nchunk * CHUNK * 4);  // shared
  int* csr1 = (int*)carve((size_t)E * 4);
  int* csr2 = (int*)carve((size_t)E * 4);
  __half* H = (__half*)carve((size_t)N * 64 * 2);

  const int aggblk = (N * 64 + 255) / 256;  // 25000

  hipMemsetAsync(btot12, 0, (size_t)2 * MAXB * 4, stream);

  // layer 1
  k_scatter<<<nchunk, 256, 0, stream>>>(src0, dst0, runoff, btot1, packed, E, B);
  k_btot<<<1, 1024, 0, stream>>>(btot1, bbase1, B, E);
  k_bfin<<<B, 256, 0, stream>>>(packed, runoff, bbase1, off1, dinv1, csr1, N, B, nchunk);
  k_gemm64<<<2048, 256, 0, stream>>>(x, W1, dinv1, H, N);
  k_agg<true><<<aggblk, 256, 0, stream>>>(H, csr1, off1, dinv1, b1, out, N);

  // layer 2 (runoff/packed reused; stream order serializes)
  k_scatter<<<nchunk, 256, 0, stream>>>(src1, dst1, runoff, btot2, packed, E, B);
  k_btot<<<1, 1024, 0, stream>>>(btot2, bbase2, B, E);
  k_bfin<<<B, 256, 0, stream>>>(packed, runoff, bbase2, off2, dinv2, csr2, N, B, nchunk);
  k_gemm64<<<2048, 256, 0, stream>>>(out, W2, dinv2, H, N);
  k_agg<false><<<aggblk, 256, 0, stream>>>(H, csr2, off2, dinv2, b2, out, N);
}

// Round 6
// 617.634 us; speedup vs baseline: 1.0517x; 1.0517x over previous
//
#include <hip/hip_runtime.h>
#include <hip/hip_fp16.h>

// 2-layer GCN: out = gcn(relu(gcn(x,W1,b1,e0)), W2, b2, e1)
// R1: atomic-cursor CSR fill -> 16x write-amp -> bucket partition.
// R2: node-granular global-atomic histogram -> bucket histogram + fused
//     per-bucket finalize; dinv folded into GEMM epilogue (H' fp16 since R3).
// R4: block-private chunk regions (write-amp 1.0 in theory)...
// R5: ...measured 7x write-amp anyway: runs written temporally scattered
//     while streaming reads thrash L2 -> partial-line evictions. Fix:
//     sort each chunk IN LDS (stage -> hist/scan -> LDS scatter) and write
//     packed[] with sequential coalesced stores (each line written once).
//     CHUNK 16384->4096 (782 blocks, 3/CU) fixes scatter starvation.
//     Run-offset table transposed (tiled) so scatter writes AND bfin reads
//     are both coalesced; bfin goes thread-per-run.

#define NPB   128
#define BSH   7
#define BMSK  127
#define MAXB  1024          // >= B = ceil(100000/128) = 782
#define ROST  (MAXB + 1)    // runoff row stride
#define CHUNK 4096
#define MAXCH 1024          // >= nchunk = ceil(E/CHUNK) = 782

// Sort chunk k by dst-bucket entirely in LDS; write packed[] coalesced.
// Emits runoff[k][b] (run starts, exclusive prefix; [k][B]=chunk count) and
// accumulates bucket totals into btot.
__global__ __launch_bounds__(256) void k_scatter(const int* __restrict__ src,
                                                 const int* __restrict__ dst,
                                                 int* __restrict__ runoff,
                                                 int* __restrict__ btot,
                                                 int* __restrict__ packed,
                                                 int E, int B) {
  __shared__ int stage[CHUNK];
  __shared__ int sorted[CHUNK];
  __shared__ unsigned short bkt[CHUNK];
  __shared__ int hist[MAXB];
  __shared__ int wsum[4];
  int t = threadIdx.x;
  int k = blockIdx.x;
  int e0 = k * CHUNK;
  int cnt = min(CHUNK, E - e0);
  for (int b = t; b < B; b += 256) hist[b] = 0;
  __syncthreads();
  // pass 1: load, pack, stage in LDS, bucket-histogram
  if (cnt == CHUNK) {
#pragma unroll
    for (int r = 0; r < 16; r += 4) {
      int i0 = (r + 0) * 256 + t, i1 = (r + 1) * 256 + t;
      int i2 = (r + 2) * 256 + t, i3 = (r + 3) * 256 + t;
      int d0 = dst[e0 + i0], d1 = dst[e0 + i1];
      int d2 = dst[e0 + i2], d3 = dst[e0 + i3];
      int s0 = src[e0 + i0], s1 = src[e0 + i1];
      int s2 = src[e0 + i2], s3 = src[e0 + i3];
      stage[i0] = (s0 << BSH) | (d0 & BMSK); bkt[i0] = (unsigned short)(d0 >> BSH);
      stage[i1] = (s1 << BSH) | (d1 & BMSK); bkt[i1] = (unsigned short)(d1 >> BSH);
      stage[i2] = (s2 << BSH) | (d2 & BMSK); bkt[i2] = (unsigned short)(d2 >> BSH);
      stage[i3] = (s3 << BSH) | (d3 & BMSK); bkt[i3] = (unsigned short)(d3 >> BSH);
      atomicAdd(&hist[d0 >> BSH], 1);
      atomicAdd(&hist[d1 >> BSH], 1);
      atomicAdd(&hist[d2 >> BSH], 1);
      atomicAdd(&hist[d3 >> BSH], 1);
    }
  } else {
    for (int i = t; i < cnt; i += 256) {
      int d = dst[e0 + i], s = src[e0 + i];
      stage[i] = (s << BSH) | (d & BMSK);
      bkt[i] = (unsigned short)(d >> BSH);
      atomicAdd(&hist[d >> BSH], 1);
    }
  }
  __syncthreads();
  // scan B bins (256 threads x 4)
  int i0 = t * 4;
  int v0 = (i0 + 0 < B) ? hist[i0 + 0] : 0;
  int v1 = (i0 + 1 < B) ? hist[i0 + 1] : 0;
  int v2 = (i0 + 2 < B) ? hist[i0 + 2] : 0;
  int v3 = (i0 + 3 < B) ? hist[i0 + 3] : 0;
  if (v0) atomicAdd(&btot[i0 + 0], v0);
  if (v1) atomicAdd(&btot[i0 + 1], v1);
  if (v2) atomicAdd(&btot[i0 + 2], v2);
  if (v3) atomicAdd(&btot[i0 + 3], v3);
  int tsum = v0 + v1 + v2 + v3;
  int lane = t & 63, wid = t >> 6;
  int x = tsum;
#pragma unroll
  for (int d = 1; d < 64; d <<= 1) {
    int y = __shfl_up(x, d, 64);
    if (lane >= d) x += y;
  }
  if (lane == 63) wsum[wid] = x;
  __syncthreads();
  int wofs = 0;
  for (int ww = 0; ww < wid; ++ww) wofs += wsum[ww];
  int excl = wofs + x - tsum;
  hist[i0 + 0] = excl;
  hist[i0 + 1] = excl + v0;
  hist[i0 + 2] = excl + v0 + v1;
  hist[i0 + 3] = excl + v0 + v1 + v2;
  __syncthreads();
  // write run-offset row (contiguous, dense) BEFORE cursors get bumped
  int* row = runoff + (size_t)k * ROST;
  for (int b = t; b < B; b += 256) row[b] = hist[b];
  if (t == 0) row[B] = cnt;
  __syncthreads();
  // pass 2: LDS -> LDS scatter (hist doubles as cursor)
  for (int i = t; i < cnt; i += 256) {
    int pos = atomicAdd(&hist[bkt[i]], 1);
    sorted[pos] = stage[i];
  }
  __syncthreads();
  // pass 3: coalesced sequential writeout -- each line written exactly once
  for (int i = t; i < cnt; i += 256) packed[e0 + i] = sorted[i];
}

// Exclusive scan of bucket totals -> bbase[0..B], bbase[B]=E. One block.
__global__ __launch_bounds__(1024) void k_btot(const int* __restrict__ btot,
                                               int* __restrict__ bbase,
                                               int B, int E) {
  __shared__ int wsum[16];
  int t = threadIdx.x;
  int c = (t < B) ? btot[t] : 0;
  int lane = t & 63, wid = t >> 6;
  int x = c;
#pragma unroll
  for (int d = 1; d < 64; d <<= 1) {
    int y = __shfl_up(x, d, 64);
    if (lane >= d) x += y;
  }
  if (lane == 63) wsum[wid] = x;
  __syncthreads();
  int wofs = 0;
  for (int ww = 0; ww < wid; ++ww) wofs += wsum[ww];
  if (t < B) bbase[t] = wofs + x - c;
  if (t == 0) bbase[B] = E;
}

// Tiled transpose: AT[b][k] = A[k][b].  A rows=nchunk (stride ROST),
// AT rows=B+1 (stride MAXCH). Both sides coalesced via LDS tile.
__global__ __launch_bounds__(256) void k_transpose(const int* __restrict__ A,
                                                   int* __restrict__ AT,
                                                   int rows, int cols) {
  __shared__ int tile[32][33];
  int bx = blockIdx.x * 32;  // col (b)
  int by = blockIdx.y * 32;  // row (k)
  int tx = threadIdx.x & 31, ty = threadIdx.x >> 5;
#pragma unroll
  for (int q = 0; q < 4; ++q) {
    int r = by + ty + q * 8, c = bx + tx;
    if (r < rows && c < cols) tile[ty + q * 8][tx] = A[(size_t)r * ROST + c];
  }
  __syncthreads();
#pragma unroll
  for (int q = 0; q < 4; ++q) {
    int c = bx + ty + q * 8;  // b
    int r = by + tx;          // k
    if (c < cols && r < rows) AT[(size_t)c * MAXCH + r] = tile[tx][ty + q * 8];
  }
}

// Per-bucket finalize: thread-per-run streaming -> LDS node counts -> scan
// -> off/dinv -> csr fill into this bucket's contiguous window.
__global__ __launch_bounds__(256) void k_bfin(const int* __restrict__ packed,
                                              const int* __restrict__ runoffT,
                                              const int* __restrict__ bbase,
                                              int* __restrict__ off,
                                              float* __restrict__ dinv,
                                              int* __restrict__ csr,
                                              int N, int B, int nchunk) {
  __shared__ int cnt[NPB];
  __shared__ int cur[NPB];
  __shared__ int rs[MAXCH];
  __shared__ unsigned short rl[MAXCH];
  __shared__ int wsum[4];
  int t = threadIdx.x;
  int b = blockIdx.x;
  for (int k = t; k < nchunk; k += 256) {
    int s = runoffT[(size_t)b * MAXCH + k];
    int e = runoffT[(size_t)(b + 1) * MAXCH + k];
    rs[k] = k * CHUNK + s;
    rl[k] = (unsigned short)(e - s);
  }
  if (t < NPB) cnt[t] = 0;
  __syncthreads();
  // pass 1: per-node counts (thread-per-run)
  for (int k = t; k < nchunk; k += 256) {
    int base = rs[k], len = rl[k];
    for (int j = 0; j < len; ++j)
      atomicAdd(&cnt[packed[base + j] & BMSK], 1);
  }
  __syncthreads();
  int lane = t & 63, w = t >> 6;
  int c = (t < NPB) ? cnt[t] : 0;
  int x = c;
#pragma unroll
  for (int d = 1; d < 64; d <<= 1) {
    int y = __shfl_up(x, d, 64);
    if (lane >= d) x += y;
  }
  if (lane == 63) wsum[w] = x;
  __syncthreads();
  int wofs = 0;
  for (int ww = 0; ww < w; ++ww) wofs += wsum[ww];
  int excl = bbase[b] + wofs + x - c;
  int v = (b << BSH) + t;
  if (t < NPB && v < N) {
    off[v] = excl;
    dinv[v] = rsqrtf((float)(c + 1));  // +1 self-loop
  }
  if (t < NPB) cur[t] = excl;
  if (b == B - 1 && t == 0) off[N] = bbase[B];
  __syncthreads();
  // pass 2: csr fill (bucket window written in one short dense burst)
  for (int k = t; k < nchunk; k += 256) {
    int base = rs[k], len = rl[k];
    for (int j = 0; j < len; ++j) {
      int e = packed[base + j];
      int p = atomicAdd(&cur[e & BMSK], 1);
      csr[p] = e >> BSH;
    }
  }
}

// H'[v] = fp16((X @ W)[v] * dinv[v]).  W (16KB) in LDS; 4 nodes/block-iter.
__global__ __launch_bounds__(256) void k_gemm64(const float* __restrict__ X,
                                                const float* __restrict__ W,
                                                const float* __restrict__ dinv,
                                                __half* __restrict__ H, int N) {
  __shared__ float Wl[4096];
  __shared__ float Xl[256];
  for (int t = threadIdx.x; t < 4096; t += 256) Wl[t] = W[t];
  int j = threadIdx.x & 63;
  int nl = threadIdx.x >> 6;
  for (int base = blockIdx.x * 4; base < N; base += gridDim.x * 4) {
    __syncthreads();
    int gi = base * 64 + threadIdx.x;
    Xl[threadIdx.x] = (gi < N * 64) ? X[gi] : 0.f;
    __syncthreads();
    int v = base + nl;
    if (v < N) {
      float acc = 0.f;
#pragma unroll
      for (int k = 0; k < 64; k += 4) {
        acc = fmaf(Xl[nl * 64 + k + 0], Wl[(k + 0) * 64 + j], acc);
        acc = fmaf(Xl[nl * 64 + k + 1], Wl[(k + 1) * 64 + j], acc);
        acc = fmaf(Xl[nl * 64 + k + 2], Wl[(k + 2) * 64 + j], acc);
        acc = fmaf(Xl[nl * 64 + k + 3], Wl[(k + 3) * 64 + j], acc);
      }
      H[v * 64 + j] = __float2half_rn(acc * dinv[v]);
    }
  }
}

// Pull aggregation: one wave per node, lane = feature; fp16 gathers,
// fp32 accumulate. csr read 64-per-wave-load, shfl-broadcast.
template <bool RELU>
__global__ __launch_bounds__(256) void k_agg(const __half* __restrict__ H,
                                             const int* __restrict__ csr,
                                             const int* __restrict__ off,
                                             const float* __restrict__ dinv,
                                             const float* __restrict__ bias,
                                             float* __restrict__ out, int N) {
  int wid = (blockIdx.x * blockDim.x + threadIdx.x) >> 6;
  int lane = threadIdx.x & 63;
  if (wid >= N) return;
  int beg = off[wid];
  int num = off[wid + 1] - beg;
  float acc = __half2float(H[wid * 64 + lane]);  // self-loop (pre-scaled)
  for (int base = 0; base < num; base += 64) {
    int navail = min(64, num - base);
    int sv = (base + lane < num) ? csr[beg + base + lane] : 0;
    int j = 0;
    for (; j + 4 <= navail; j += 4) {
      int s0 = __shfl(sv, j + 0), s1 = __shfl(sv, j + 1);
      int s2 = __shfl(sv, j + 2), s3 = __shfl(sv, j + 3);
      float h0 = __half2float(H[s0 * 64 + lane]);
      float h1 = __half2float(H[s1 * 64 + lane]);
      float h2 = __half2float(H[s2 * 64 + lane]);
      float h3 = __half2float(H[s3 * 64 + lane]);
      acc += h0; acc += h1; acc += h2; acc += h3;
    }
    for (; j < navail; ++j) acc += __half2float(H[__shfl(sv, j) * 64 + lane]);
  }
  acc = fmaf(acc, dinv[wid], bias[lane]);
  if (RELU) acc = fmaxf(acc, 0.f);
  out[wid * 64 + lane] = acc;
}

extern "C" void kernel_launch(void* const* d_in, const int* in_sizes, int n_in,
                              void* d_out, int out_size, void* d_ws, size_t ws_size,
                              hipStream_t stream) {
  const float* x  = (const float*)d_in[0];
  const float* W1 = (const float*)d_in[1];
  const float* b1 = (const float*)d_in[2];
  const float* W2 = (const float*)d_in[3];
  const float* b2 = (const float*)d_in[4];
  const int*   e0 = (const int*)d_in[5];
  const int*   e1 = (const int*)d_in[6];
  float* out = (float*)d_out;

  const int N = in_sizes[0] / 64;      // 100000
  const int E = in_sizes[5] / 2;       // 3200000
  const int B = (N + NPB - 1) / NPB;   // 782
  const int nchunk = (E + CHUNK - 1) / CHUNK;  // 782
  const int* src0 = e0;     const int* dst0 = e0 + E;
  const int* src1 = e1;     const int* dst1 = e1 + E;

  char* w = (char*)d_ws;
  size_t o = 0;
  auto carve = [&](size_t bytes) -> void* {
    void* p = w + o;
    o = (o + bytes + 255) & ~(size_t)255;
    return p;
  };
  int* btot12 = (int*)carve((size_t)2 * MAXB * 4);  // zero-init
  int* btot1 = btot12;
  int* btot2 = btot12 + MAXB;
  int* bbase = (int*)carve((MAXB + 1) * 4);
  int* runoff = (int*)carve((size_t)MAXCH * ROST * 4);        // shared
  int* runoffT = (int*)carve((size_t)(MAXB + 1) * MAXCH * 4); // shared
  int* off = (int*)carve((size_t)(N + 1) * 4);     // shared (serialized)
  float* dinv = (float*)carve((size_t)N * 4);      // shared (serialized)
  int* packed = (int*)carve((size_t)nchunk * CHUNK * 4);  // shared
  int* csr = (int*)carve((size_t)E * 4);           // shared (serialized)
  __half* H = (__half*)carve((size_t)N * 64 * 2);

  const int aggblk = (N * 64 + 255) / 256;  // 25000
  const dim3 tgrid((B + 1 + 31) / 32, (nchunk + 31) / 32);

  hipMemsetAsync(btot12, 0, (size_t)2 * MAXB * 4, stream);

  // layer 1
  k_scatter<<<nchunk, 256, 0, stream>>>(src0, dst0, runoff, btot1, packed, E, B);
  k_btot<<<1, 1024, 0, stream>>>(btot1, bbase, B, E);
  k_transpose<<<tgrid, 256, 0, stream>>>(runoff, runoffT, nchunk, B + 1);
  k_bfin<<<B, 256, 0, stream>>>(packed, runoffT, bbase, off, dinv, csr, N, B, nchunk);
  k_gemm64<<<2048, 256, 0, stream>>>(x, W1, dinv, H, N);
  k_agg<true><<<aggblk, 256, 0, stream>>>(H, csr, off, dinv, b1, out, N);

  // layer 2 (all scratch reused; stream order serializes)
  k_scatter<<<nchunk, 256, 0, stream>>>(src1, dst1, runoff, btot2, packed, E, B);
  k_btot<<<1, 1024, 0, stream>>>(btot2, bbase, B, E);
  k_transpose<<<tgrid, 256, 0, stream>>>(runoff, runoffT, nchunk, B + 1);
  k_bfin<<<B, 256, 0, stream>>>(packed, runoffT, bbase, off, dinv, csr, N, B, nchunk);
  k_gemm64<<<2048, 256, 0, stream>>>(out, W2, dinv, H, N);
  k_agg<false><<<aggblk, 256, 0, stream>>>(H, csr, off, dinv, b2, out, N);
}